// Round 9
// baseline (432.601 us; speedup 1.0000x reference)
//
#include <hip/hip_runtime.h>

#define HW 65536
#define W_IMG 256
#define H_IMG 256
#define CIN 64
#define CHID 384
#define CQK 128

// ---------------- K1: 1x1 expansion GEMM (LDS-free streaming) ----------------
// block = 48co x 256px as TWO sequential 24-co subtiles; 4 waves; wave owns
// 6co per subtile. Peak VGPR ~54 (<=64 -> 8 waves/SIMD); grid 256x8 = 2048
// blocks = exactly 8 blocks/CU in ONE residency round.
__global__ __launch_bounds__(256) void k1_expand(
    const float* __restrict__ x_base,    // [B][CIN][HW]
    const float* __restrict__ wh,        // [CHID][CIN]
    const float* __restrict__ bh,        // [CHID]
    float* __restrict__ hidden_base,     // [B][CHID][HW]
    size_t x_bstride, size_t hid_bstride)
{
    const float* x = x_base + blockIdx.z * x_bstride;
    float* hidden  = hidden_base + blockIdx.z * hid_bstride;
    const int pxbase = blockIdx.x * 256;
    const int cobase = blockIdx.y * 48;
    const int tid  = threadIdx.x;
    const int lane = tid & 63;
    const int wq   = __builtin_amdgcn_readfirstlane(tid >> 6);
    const int px   = pxbase + lane * 4;

    #pragma unroll
    for (int st = 0; st < 2; ++st) {
        const int cw = cobase + st * 24 + wq * 6;   // wave-uniform
        float acc[6][4];
        #pragma unroll
        for (int i = 0; i < 6; ++i)
            #pragma unroll
            for (int j = 0; j < 4; ++j) acc[i][j] = 0.f;

        #pragma unroll 2
        for (int ci4 = 0; ci4 < CIN; ci4 += 4) {
            float4 xv[4];
            #pragma unroll
            for (int u = 0; u < 4; ++u)
                xv[u] = *reinterpret_cast<const float4*>(&x[(size_t)(ci4 + u) * HW + px]);
            #pragma unroll
            for (int i = 0; i < 6; ++i) {
                // wave-uniform address -> s_load_dwordx4 (SGPR weights)
                float4 wv = *reinterpret_cast<const float4*>(
                    &wh[(size_t)(cw + i) * CIN + ci4]);
                float wu[4] = {wv.x, wv.y, wv.z, wv.w};
                #pragma unroll
                for (int u = 0; u < 4; ++u) {
                    acc[i][0] += wu[u] * xv[u].x;
                    acc[i][1] += wu[u] * xv[u].y;
                    acc[i][2] += wu[u] * xv[u].z;
                    acc[i][3] += wu[u] * xv[u].w;
                }
            }
        }

        #pragma unroll
        for (int i = 0; i < 6; ++i) {
            int co = cw + i;
            float b = bh[co];
            float4 o;
            o.x = acc[i][0] + b; o.y = acc[i][1] + b;
            o.z = acc[i][2] + b; o.w = acc[i][3] + b;
            *reinterpret_cast<float4*>(&hidden[(size_t)co * HW + px]) = o;
        }
    }
}

// ---------------- K2: fused depthwise 3x3 + 8x8 circular conv + v-mul ----------------
// v6: async k-channel stage — q,k global loads issued back-to-back into regs;
// k's ds_write happens after dw-q (latency hidden); halo zeroed once at entry.
#define QK_CH   2208   // 8*276 floats
#define QK_ROW  276
#define QK_SEG  68
__global__ __launch_bounds__(256) void k2_fused(
    const float* __restrict__ hidden_base,  // [B][CHID][HW]
    const float* __restrict__ wdw,          // [CHID][9]
    const float* __restrict__ bdw,          // [CHID]
    float* __restrict__ vout_base,          // [B][CQK][HW]
    size_t hid_bstride, size_t vout_bstride)
{
    __shared__ float stg[10 * 264];      // one channel; pixel w at col w+4
    __shared__ float qk[2 * QK_CH];      // depthwise q,k

    const float* hidden = hidden_base + blockIdx.z * hid_bstride;
    float* vout         = vout_base + blockIdx.z * vout_bstride;

    const int c  = blockIdx.y;
    const int r0 = blockIdx.x * 8;
    const int tid = threadIdx.x;

    const int row = tid >> 5;
    const int seg = (tid >> 3) & 3;
    const int i   = tid & 7;
    const int gr  = r0 + row;
    const int wp0 = seg * 64 + i * 8;

    // staging geometry: f4 index = it*256+tid over [0,640): lr = f4>>6, p4 = f4&63
    // ---- issue q loads -> regs (needed first)
    float4 qreg[3];
    #pragma unroll
    for (int it = 0; it < 3; ++it) {
        int f4 = it * 256 + tid;
        qreg[it] = make_float4(0.f, 0.f, 0.f, 0.f);
        if (f4 < 640) {
            int lr = f4 >> 6, p4 = f4 & 63;
            int grr = r0 - 1 + lr;
            if ((unsigned)grr < H_IMG)
                qreg[it] = *reinterpret_cast<const float4*>(
                    &hidden[(size_t)c * HW + (size_t)grr * W_IMG + p4 * 4]);
        }
    }
    // ---- issue k loads -> regs (latency spans dw-q)
    float4 kreg[3];
    #pragma unroll
    for (int it = 0; it < 3; ++it) {
        int f4 = it * 256 + tid;
        kreg[it] = make_float4(0.f, 0.f, 0.f, 0.f);
        if (f4 < 640) {
            int lr = f4 >> 6, p4 = f4 & 63;
            int grr = r0 - 1 + lr;
            if ((unsigned)grr < H_IMG)
                kreg[it] = *reinterpret_cast<const float4*>(
                    &hidden[(size_t)(c + CQK) * HW + (size_t)grr * W_IMG + p4 * 4]);
        }
    }

    // ---- write q -> LDS (compiler waits on q loads only); zero halo once
    #pragma unroll
    for (int it = 0; it < 3; ++it) {
        int f4 = it * 256 + tid;
        if (f4 < 640) {
            int lr = f4 >> 6, p4 = f4 & 63;
            *reinterpret_cast<float4*>(&stg[lr * 264 + 4 + p4 * 4]) = qreg[it];
        }
    }
    if (tid < 10) {                      // cols 3,260 never touched by staging
        stg[tid * 264 + 3]   = 0.f;
        stg[tid * 264 + 260] = 0.f;
    }

    // ---- issue v loads (needed in conv phase; hides under dw-q + dw-k)
    const float* hbv = hidden + (size_t)(c + 2 * CQK) * HW;
    float4 hv[3][2];
    float  hm[3], hp[3];
    #pragma unroll
    for (int ky = 0; ky < 3; ++ky) {
        int grr = gr + ky - 1;
        hv[ky][0] = make_float4(0.f, 0.f, 0.f, 0.f);
        hv[ky][1] = make_float4(0.f, 0.f, 0.f, 0.f);
        hm[ky] = 0.f; hp[ky] = 0.f;
        if ((unsigned)grr < H_IMG) {
            const float* rb = hbv + (size_t)grr * W_IMG;
            hv[ky][0] = *reinterpret_cast<const float4*>(&rb[wp0]);
            hv[ky][1] = *reinterpret_cast<const float4*>(&rb[wp0 + 4]);
            hm[ky] = (wp0 > 0)   ? rb[wp0 - 1] : 0.f;
            hp[ky] = (wp0 < 248) ? rb[wp0 + 8] : 0.f;
        }
    }

    const int w = tid;
    const int segw = w >> 6;
    const int tw   = w & 63;

    // ---- dw for q (ch 0) then k (ch 1); k restaged from regs between syncs
    #pragma unroll
    for (int ch = 0; ch < 2; ++ch) {
        if (ch) {
            __syncthreads();             // dw-q finished reading stg
            #pragma unroll
            for (int it = 0; it < 3; ++it) {
                int f4 = it * 256 + tid;
                if (f4 < 640) {
                    int lr = f4 >> 6, p4 = f4 & 63;
                    *reinterpret_cast<float4*>(&stg[lr * 264 + 4 + p4 * 4]) = kreg[it];
                }
            }
        }
        __syncthreads();

        const float* wv = wdw + (c + ch * CQK) * 9;   // block-uniform -> scalar loads
        const float bias = bdw[c + ch * CQK];
        const float w0 = wv[0], w1 = wv[1], w2 = wv[2];
        const float w3 = wv[3], w4 = wv[4], w5 = wv[5];
        const float w6 = wv[6], w7 = wv[7], w8 = wv[8];

        const float* S0 = &stg[w + 3];
        float am = S0[0],   a0 = S0[1],   ap = S0[2];
        float bm = S0[264], b0 = S0[265], bp = S0[266];
        #pragma unroll
        for (int r = 0; r < 8; ++r) {
            const float* Sr = S0 + (r + 2) * 264;
            float cm = Sr[0], c0 = Sr[1], cp = Sr[2];
            float a = bias + am * w0 + a0 * w1 + ap * w2
                           + bm * w3 + b0 * w4 + bp * w5
                           + cm * w6 + c0 * w7 + cp * w8;
            qk[ch * QK_CH + r * QK_ROW + segw * QK_SEG + tw] = a;
            am = bm; a0 = b0; ap = bp;
            bm = cm; b0 = c0; bp = cp;
        }
    }
    __syncthreads();

    // ---- phase 2: 8x8 circular conv + v depthwise (regs) + multiply
    const float* qb = &qk[row * QK_ROW + seg * QK_SEG];
    const float* kb = &qk[QK_CH + row * QK_ROW + seg * QK_SEG];

    float acc[8];
    #pragma unroll
    for (int j = 0; j < 8; ++j) acc[j] = 0.f;

    #pragma unroll
    for (int s = 0; s < 8; ++s) {
        int qr = (i - s) & 7;
        float4 ka = *reinterpret_cast<const float4*>(&kb[s * 8]);
        float4 kc = *reinterpret_cast<const float4*>(&kb[s * 8 + 4]);
        float4 qa = *reinterpret_cast<const float4*>(&qb[qr * 8]);
        float4 qc = *reinterpret_cast<const float4*>(&qb[qr * 8 + 4]);
        float kr[8] = {ka.x, ka.y, ka.z, ka.w, kc.x, kc.y, kc.z, kc.w};
        float qv[8] = {qa.x, qa.y, qa.z, qa.w, qc.x, qc.y, qc.z, qc.w};
        #pragma unroll
        for (int t = 0; t < 8; ++t)
            #pragma unroll
            for (int j = 0; j < 8; ++j)
                acc[j] += kr[t] * qv[(j - t) & 7];
    }

    const float* wvv = wdw + (c + 2 * CQK) * 9;
    const float vbias = bdw[c + 2 * CQK];
    float vc[8];
    #pragma unroll
    for (int j = 0; j < 8; ++j) vc[j] = vbias;
    #pragma unroll
    for (int ky = 0; ky < 3; ++ky) {
        float kw0 = wvv[ky * 3], kw1 = wvv[ky * 3 + 1], kw2 = wvv[ky * 3 + 2];
        float h[10];
        h[0] = hm[ky];
        h[1] = hv[ky][0].x; h[2] = hv[ky][0].y; h[3] = hv[ky][0].z; h[4] = hv[ky][0].w;
        h[5] = hv[ky][1].x; h[6] = hv[ky][1].y; h[7] = hv[ky][1].z; h[8] = hv[ky][1].w;
        h[9] = hp[ky];
        #pragma unroll
        for (int j = 0; j < 8; ++j)
            vc[j] += h[j] * kw0 + h[j + 1] * kw1 + h[j + 2] * kw2;
    }

    float* dst = &vout[(size_t)c * HW + (size_t)gr * W_IMG + wp0];
    float4 o0, o1;
    o0.x = acc[0] * vc[0]; o0.y = acc[1] * vc[1];
    o0.z = acc[2] * vc[2]; o0.w = acc[3] * vc[3];
    o1.x = acc[4] * vc[4]; o1.y = acc[5] * vc[5];
    o1.z = acc[6] * vc[6]; o1.w = acc[7] * vc[7];
    *reinterpret_cast<float4*>(dst)     = o0;
    *reinterpret_cast<float4*>(dst + 4) = o1;
}

// ---------------- K3: 1x1 projection GEMM (LDS-free streaming) ----------------
__global__ __launch_bounds__(256) void k3_project(
    const float* __restrict__ vout_base,  // [B][CQK][HW]
    const float* __restrict__ wo,         // [64][CQK]
    const float* __restrict__ bo,         // [64]
    float* __restrict__ out_base,         // [B][64][HW]
    size_t vout_bstride, size_t out_bstride)
{
    const float* vout = vout_base + blockIdx.z * vout_bstride;
    float* out        = out_base + blockIdx.z * out_bstride;
    const int pxbase = blockIdx.x * 256;
    const int cobase = blockIdx.y * 16;
    const int tid  = threadIdx.x;
    const int lane = tid & 63;
    const int wq   = __builtin_amdgcn_readfirstlane(tid >> 6);
    const int px   = pxbase + lane * 4;
    const int cw   = cobase + wq * 4;     // wave-uniform

    float acc[4][4];
    #pragma unroll
    for (int i = 0; i < 4; ++i)
        #pragma unroll
        for (int j = 0; j < 4; ++j) acc[i][j] = 0.f;

    #pragma unroll 2
    for (int cc4 = 0; cc4 < CQK; cc4 += 4) {
        float4 xv[4];
        #pragma unroll
        for (int u = 0; u < 4; ++u)
            xv[u] = *reinterpret_cast<const float4*>(&vout[(size_t)(cc4 + u) * HW + px]);
        #pragma unroll
        for (int i = 0; i < 4; ++i) {
            float4 wv = *reinterpret_cast<const float4*>(
                &wo[(size_t)(cw + i) * CQK + cc4]);   // uniform -> s_load
            float wu[4] = {wv.x, wv.y, wv.z, wv.w};
            #pragma unroll
            for (int u = 0; u < 4; ++u) {
                acc[i][0] += wu[u] * xv[u].x;
                acc[i][1] += wu[u] * xv[u].y;
                acc[i][2] += wu[u] * xv[u].z;
                acc[i][3] += wu[u] * xv[u].w;
            }
        }
    }

    #pragma unroll
    for (int i = 0; i < 4; ++i) {
        int co = cw + i;
        float b = bo[co];
        float4 o;
        o.x = acc[i][0] + b; o.y = acc[i][1] + b;
        o.z = acc[i][2] + b; o.w = acc[i][3] + b;
        *reinterpret_cast<float4*>(&out[(size_t)co * HW + px]) = o;
    }
}

extern "C" void kernel_launch(void* const* d_in, const int* in_sizes, int n_in,
                              void* d_out, int out_size, void* d_ws, size_t ws_size,
                              hipStream_t stream) {
    const float* x   = (const float*)d_in[0];
    const float* wh  = (const float*)d_in[1];
    const float* bh  = (const float*)d_in[2];
    const float* wdw = (const float*)d_in[3];
    const float* bdw = (const float*)d_in[4];
    const float* wo  = (const float*)d_in[5];
    const float* bo  = (const float*)d_in[6];
    float* out = (float*)d_out;

    const size_t n_hid  = (size_t)CHID * HW;
    const size_t n_vout = (size_t)CQK * HW;
    const size_t n_x    = (size_t)CIN * HW;

    if (ws_size >= 4 * (n_hid + n_vout) * sizeof(float)) {
        float* hidden = (float*)d_ws;
        float* vout   = hidden + 4 * n_hid;
        k1_expand <<<dim3(HW / 256, CHID / 48, 4), 256, 0, stream>>>(
            x, wh, bh, hidden, n_x, n_hid);
        k2_fused  <<<dim3(H_IMG / 8, CQK, 4),      256, 0, stream>>>(
            hidden, wdw, bdw, vout, n_hid, n_vout);
        k3_project<<<dim3(HW / 256, 64 / 16, 4),   256, 0, stream>>>(
            vout, wo, bo, out, n_vout, n_x);
    } else {
        float* hidden = (float*)d_ws;
        float* vout   = hidden + n_hid;
        for (int b = 0; b < 4; ++b) {
            const float* xb = x + (size_t)b * n_x;
            float* ob       = out + (size_t)b * n_x;
            k1_expand <<<dim3(HW / 256, CHID / 48, 1), 256, 0, stream>>>(
                xb, wh, bh, hidden, 0, 0);
            k2_fused  <<<dim3(H_IMG / 8, CQK, 1),      256, 0, stream>>>(
                hidden, wdw, bdw, vout, 0, 0);
            k3_project<<<dim3(HW / 256, 64 / 16, 1),   256, 0, stream>>>(
                vout, wo, bo, ob, 0, 0);
        }
    }
}

// Round 10
// 398.942 us; speedup vs baseline: 1.0844x; 1.0844x over previous
//
#include <hip/hip_runtime.h>

#define HW 65536
#define W_IMG 256
#define H_IMG 256
#define CIN 64
#define CHID 384
#define CQK 128

// ---------------- K1: 1x1 expansion GEMM (LDS-free, ping-pong prefetch) ----------------
// block = 48co x 256px, 4 waves; wave owns 12co x 256px; lane owns 12co x 4px.
// Explicit 2-deep x prefetch: 384 FMA-cycles cover ~400cyc L2/L3 latency per wave.
__global__ __launch_bounds__(256) void k1_expand(
    const float* __restrict__ x_base,    // [B][CIN][HW]
    const float* __restrict__ wh,        // [CHID][CIN]
    const float* __restrict__ bh,        // [CHID]
    float* __restrict__ hidden_base,     // [B][CHID][HW]
    size_t x_bstride, size_t hid_bstride)
{
    const float* x = x_base + blockIdx.z * x_bstride;
    float* hidden  = hidden_base + blockIdx.z * hid_bstride;
    const int pxbase = blockIdx.x * 256;
    const int cobase = blockIdx.y * 48;
    const int tid  = threadIdx.x;
    const int lane = tid & 63;
    const int wq   = __builtin_amdgcn_readfirstlane(tid >> 6);
    const int px   = pxbase + lane * 4;
    const int cw   = cobase + wq * 12;    // wave-uniform

    float acc[12][4];
    #pragma unroll
    for (int i = 0; i < 12; ++i)
        #pragma unroll
        for (int j = 0; j < 4; ++j) acc[i][j] = 0.f;

    float4 xa[4], xb[4];
    #pragma unroll
    for (int u = 0; u < 4; ++u)
        xa[u] = *reinterpret_cast<const float4*>(&x[(size_t)u * HW + px]);

    #pragma unroll 1
    for (int ci4 = 0; ci4 < CIN; ci4 += 8) {
        // prefetch second half of this 8-ci chunk
        #pragma unroll
        for (int u = 0; u < 4; ++u)
            xb[u] = *reinterpret_cast<const float4*>(&x[(size_t)(ci4 + 4 + u) * HW + px]);
        // compute on xa (192 FMA)
        #pragma unroll
        for (int i = 0; i < 12; ++i) {
            float4 wv = *reinterpret_cast<const float4*>(
                &wh[(size_t)(cw + i) * CIN + ci4]);        // wave-uniform -> s_load
            float wu[4] = {wv.x, wv.y, wv.z, wv.w};
            #pragma unroll
            for (int u = 0; u < 4; ++u) {
                acc[i][0] += wu[u] * xa[u].x;
                acc[i][1] += wu[u] * xa[u].y;
                acc[i][2] += wu[u] * xa[u].z;
                acc[i][3] += wu[u] * xa[u].w;
            }
        }
        // prefetch first half of next chunk
        if (ci4 + 8 < CIN) {
            #pragma unroll
            for (int u = 0; u < 4; ++u)
                xa[u] = *reinterpret_cast<const float4*>(&x[(size_t)(ci4 + 8 + u) * HW + px]);
        }
        // compute on xb (192 FMA)
        #pragma unroll
        for (int i = 0; i < 12; ++i) {
            float4 wv = *reinterpret_cast<const float4*>(
                &wh[(size_t)(cw + i) * CIN + ci4 + 4]);
            float wu[4] = {wv.x, wv.y, wv.z, wv.w};
            #pragma unroll
            for (int u = 0; u < 4; ++u) {
                acc[i][0] += wu[u] * xb[u].x;
                acc[i][1] += wu[u] * xb[u].y;
                acc[i][2] += wu[u] * xb[u].z;
                acc[i][3] += wu[u] * xb[u].w;
            }
        }
    }

    #pragma unroll
    for (int i = 0; i < 12; ++i) {
        int co = cw + i;
        float b = bh[co];
        float4 o;
        o.x = acc[i][0] + b; o.y = acc[i][1] + b;
        o.z = acc[i][2] + b; o.w = acc[i][3] + b;
        *reinterpret_cast<float4*>(&hidden[(size_t)co * HW + px]) = o;
    }
}

// ---------------- K2: fused depthwise 3x3 + 8x8 circular conv + v-mul ----------------
// v7: dual staging buffers (q,k loads all in flight together), ONE barrier before
// depthwise, one before phase 2; v loads stay in flight across barriers.
#define QK_CH   2208   // 8*276 floats
#define QK_ROW  276
#define QK_SEG  68
__global__ __launch_bounds__(256) void k2_fused(
    const float* __restrict__ hidden_base,  // [B][CHID][HW]
    const float* __restrict__ wdw,          // [CHID][9]
    const float* __restrict__ bdw,          // [CHID]
    float* __restrict__ vout_base,          // [B][CQK][HW]
    size_t hid_bstride, size_t vout_bstride)
{
    __shared__ float stgq[10 * 264];     // q channel; pixel w at col w+4
    __shared__ float stgk[10 * 264];     // k channel
    __shared__ float qk[2 * QK_CH];      // depthwise q,k

    const float* hidden = hidden_base + blockIdx.z * hid_bstride;
    float* vout         = vout_base + blockIdx.z * vout_bstride;

    const int c  = blockIdx.y;
    const int r0 = blockIdx.x * 8;
    const int tid = threadIdx.x;

    const int row = tid >> 5;
    const int seg = (tid >> 3) & 3;
    const int i   = tid & 7;
    const int gr  = r0 + row;
    const int wp0 = seg * 64 + i * 8;

    // ---- issue q,k staging loads back-to-back (all in flight together)
    float4 qreg[3], kreg[3];
    #pragma unroll
    for (int it = 0; it < 3; ++it) {
        int f4 = it * 256 + tid;
        qreg[it] = make_float4(0.f, 0.f, 0.f, 0.f);
        if (f4 < 640) {
            int lr = f4 >> 6, p4 = f4 & 63;
            int grr = r0 - 1 + lr;
            if ((unsigned)grr < H_IMG)
                qreg[it] = *reinterpret_cast<const float4*>(
                    &hidden[(size_t)c * HW + (size_t)grr * W_IMG + p4 * 4]);
        }
    }
    #pragma unroll
    for (int it = 0; it < 3; ++it) {
        int f4 = it * 256 + tid;
        kreg[it] = make_float4(0.f, 0.f, 0.f, 0.f);
        if (f4 < 640) {
            int lr = f4 >> 6, p4 = f4 & 63;
            int grr = r0 - 1 + lr;
            if ((unsigned)grr < H_IMG)
                kreg[it] = *reinterpret_cast<const float4*>(
                    &hidden[(size_t)(c + CQK) * HW + (size_t)grr * W_IMG + p4 * 4]);
        }
    }

    // ---- write both to LDS; zero halo cols (3, 260) for both buffers
    #pragma unroll
    for (int it = 0; it < 3; ++it) {
        int f4 = it * 256 + tid;
        if (f4 < 640) {
            int lr = f4 >> 6, p4 = f4 & 63;
            *reinterpret_cast<float4*>(&stgq[lr * 264 + 4 + p4 * 4]) = qreg[it];
            *reinterpret_cast<float4*>(&stgk[lr * 264 + 4 + p4 * 4]) = kreg[it];
        }
    }
    if (tid < 10) {
        stgq[tid * 264 + 3]   = 0.f;
        stgq[tid * 264 + 260] = 0.f;
        stgk[tid * 264 + 3]   = 0.f;
        stgk[tid * 264 + 260] = 0.f;
    }

    // ---- issue v loads (consumed in phase 2; stay in flight across barriers)
    const float* hbv = hidden + (size_t)(c + 2 * CQK) * HW;
    float4 hv[3][2];
    float  hm[3], hp[3];
    #pragma unroll
    for (int ky = 0; ky < 3; ++ky) {
        int grr = gr + ky - 1;
        hv[ky][0] = make_float4(0.f, 0.f, 0.f, 0.f);
        hv[ky][1] = make_float4(0.f, 0.f, 0.f, 0.f);
        hm[ky] = 0.f; hp[ky] = 0.f;
        if ((unsigned)grr < H_IMG) {
            const float* rb = hbv + (size_t)grr * W_IMG;
            hv[ky][0] = *reinterpret_cast<const float4*>(&rb[wp0]);
            hv[ky][1] = *reinterpret_cast<const float4*>(&rb[wp0 + 4]);
            hm[ky] = (wp0 > 0)   ? rb[wp0 - 1] : 0.f;
            hp[ky] = (wp0 < 248) ? rb[wp0 + 8] : 0.f;
        }
    }

    __syncthreads();                     // single barrier: staging complete

    const int w = tid;
    const int segw = w >> 6;
    const int tw   = w & 63;

    // ---- depthwise q then k, no intervening sync
    #pragma unroll
    for (int ch = 0; ch < 2; ++ch) {
        const float* S = ch ? stgk : stgq;
        const float* wv = wdw + (c + ch * CQK) * 9;   // block-uniform -> scalar loads
        const float bias = bdw[c + ch * CQK];
        const float w0 = wv[0], w1 = wv[1], w2 = wv[2];
        const float w3 = wv[3], w4 = wv[4], w5 = wv[5];
        const float w6 = wv[6], w7 = wv[7], w8 = wv[8];

        const float* S0 = S + w + 3;
        float am = S0[0],   a0 = S0[1],   ap = S0[2];
        float bm = S0[264], b0 = S0[265], bp = S0[266];
        #pragma unroll
        for (int r = 0; r < 8; ++r) {
            const float* Sr = S0 + (r + 2) * 264;
            float cm = Sr[0], c0 = Sr[1], cp = Sr[2];
            float a = bias + am * w0 + a0 * w1 + ap * w2
                           + bm * w3 + b0 * w4 + bp * w5
                           + cm * w6 + c0 * w7 + cp * w8;
            qk[ch * QK_CH + r * QK_ROW + segw * QK_SEG + tw] = a;
            am = bm; a0 = b0; ap = bp;
            bm = cm; b0 = c0; bp = cp;
        }
    }
    __syncthreads();

    // ---- phase 2: 8x8 circular conv + v depthwise (regs) + multiply
    const float* qb = &qk[row * QK_ROW + seg * QK_SEG];
    const float* kb = &qk[QK_CH + row * QK_ROW + seg * QK_SEG];

    float acc[8];
    #pragma unroll
    for (int j = 0; j < 8; ++j) acc[j] = 0.f;

    #pragma unroll
    for (int s = 0; s < 8; ++s) {
        int qr = (i - s) & 7;
        float4 ka = *reinterpret_cast<const float4*>(&kb[s * 8]);
        float4 kc = *reinterpret_cast<const float4*>(&kb[s * 8 + 4]);
        float4 qa = *reinterpret_cast<const float4*>(&qb[qr * 8]);
        float4 qc = *reinterpret_cast<const float4*>(&qb[qr * 8 + 4]);
        float kr[8] = {ka.x, ka.y, ka.z, ka.w, kc.x, kc.y, kc.z, kc.w};
        float qv[8] = {qa.x, qa.y, qa.z, qa.w, qc.x, qc.y, qc.z, qc.w};
        #pragma unroll
        for (int t = 0; t < 8; ++t)
            #pragma unroll
            for (int j = 0; j < 8; ++j)
                acc[j] += kr[t] * qv[(j - t) & 7];
    }

    const float* wvv = wdw + (c + 2 * CQK) * 9;
    const float vbias = bdw[c + 2 * CQK];
    float vc[8];
    #pragma unroll
    for (int j = 0; j < 8; ++j) vc[j] = vbias;
    #pragma unroll
    for (int ky = 0; ky < 3; ++ky) {
        float kw0 = wvv[ky * 3], kw1 = wvv[ky * 3 + 1], kw2 = wvv[ky * 3 + 2];
        float h[10];
        h[0] = hm[ky];
        h[1] = hv[ky][0].x; h[2] = hv[ky][0].y; h[3] = hv[ky][0].z; h[4] = hv[ky][0].w;
        h[5] = hv[ky][1].x; h[6] = hv[ky][1].y; h[7] = hv[ky][1].z; h[8] = hv[ky][1].w;
        h[9] = hp[ky];
        #pragma unroll
        for (int j = 0; j < 8; ++j)
            vc[j] += h[j] * kw0 + h[j + 1] * kw1 + h[j + 2] * kw2;
    }

    float* dst = &vout[(size_t)c * HW + (size_t)gr * W_IMG + wp0];
    float4 o0, o1;
    o0.x = acc[0] * vc[0]; o0.y = acc[1] * vc[1];
    o0.z = acc[2] * vc[2]; o0.w = acc[3] * vc[3];
    o1.x = acc[4] * vc[4]; o1.y = acc[5] * vc[5];
    o1.z = acc[6] * vc[6]; o1.w = acc[7] * vc[7];
    *reinterpret_cast<float4*>(dst)     = o0;
    *reinterpret_cast<float4*>(dst + 4) = o1;
}

// ---------------- K3: 1x1 projection GEMM (LDS-free, ping-pong prefetch) ----------------
// block = 16co x 256px, 4 waves; wave owns 4co x 256px; lane owns 4co x 4px.
__global__ __launch_bounds__(256) void k3_project(
    const float* __restrict__ vout_base,  // [B][CQK][HW]
    const float* __restrict__ wo,         // [64][CQK]
    const float* __restrict__ bo,         // [64]
    float* __restrict__ out_base,         // [B][64][HW]
    size_t vout_bstride, size_t out_bstride)
{
    const float* vout = vout_base + blockIdx.z * vout_bstride;
    float* out        = out_base + blockIdx.z * out_bstride;
    const int pxbase = blockIdx.x * 256;
    const int cobase = blockIdx.y * 16;
    const int tid  = threadIdx.x;
    const int lane = tid & 63;
    const int wq   = __builtin_amdgcn_readfirstlane(tid >> 6);
    const int px   = pxbase + lane * 4;
    const int cw   = cobase + wq * 4;     // wave-uniform

    float acc[4][4];
    #pragma unroll
    for (int i = 0; i < 4; ++i)
        #pragma unroll
        for (int j = 0; j < 4; ++j) acc[i][j] = 0.f;

    float4 xa[4], xb[4];
    #pragma unroll
    for (int u = 0; u < 4; ++u)
        xa[u] = *reinterpret_cast<const float4*>(&vout[(size_t)u * HW + px]);

    #pragma unroll 1
    for (int cc4 = 0; cc4 < CQK; cc4 += 8) {
        #pragma unroll
        for (int u = 0; u < 4; ++u)
            xb[u] = *reinterpret_cast<const float4*>(&vout[(size_t)(cc4 + 4 + u) * HW + px]);
        #pragma unroll
        for (int i = 0; i < 4; ++i) {
            float4 wv = *reinterpret_cast<const float4*>(
                &wo[(size_t)(cw + i) * CQK + cc4]);   // uniform -> s_load
            float wu[4] = {wv.x, wv.y, wv.z, wv.w};
            #pragma unroll
            for (int u = 0; u < 4; ++u) {
                acc[i][0] += wu[u] * xa[u].x;
                acc[i][1] += wu[u] * xa[u].y;
                acc[i][2] += wu[u] * xa[u].z;
                acc[i][3] += wu[u] * xa[u].w;
            }
        }
        if (cc4 + 8 < CQK) {
            #pragma unroll
            for (int u = 0; u < 4; ++u)
                xa[u] = *reinterpret_cast<const float4*>(&vout[(size_t)(cc4 + 8 + u) * HW + px]);
        }
        #pragma unroll
        for (int i = 0; i < 4; ++i) {
            float4 wv = *reinterpret_cast<const float4*>(
                &wo[(size_t)(cw + i) * CQK + cc4 + 4]);
            float wu[4] = {wv.x, wv.y, wv.z, wv.w};
            #pragma unroll
            for (int u = 0; u < 4; ++u) {
                acc[i][0] += wu[u] * xb[u].x;
                acc[i][1] += wu[u] * xb[u].y;
                acc[i][2] += wu[u] * xb[u].z;
                acc[i][3] += wu[u] * xb[u].w;
            }
        }
    }

    #pragma unroll
    for (int i = 0; i < 4; ++i) {
        int co = cw + i;
        float b = bo[co];
        float4 o;
        o.x = acc[i][0] + b; o.y = acc[i][1] + b;
        o.z = acc[i][2] + b; o.w = acc[i][3] + b;
        *reinterpret_cast<float4*>(&out[(size_t)co * HW + px]) = o;
    }
}

extern "C" void kernel_launch(void* const* d_in, const int* in_sizes, int n_in,
                              void* d_out, int out_size, void* d_ws, size_t ws_size,
                              hipStream_t stream) {
    const float* x   = (const float*)d_in[0];
    const float* wh  = (const float*)d_in[1];
    const float* bh  = (const float*)d_in[2];
    const float* wdw = (const float*)d_in[3];
    const float* bdw = (const float*)d_in[4];
    const float* wo  = (const float*)d_in[5];
    const float* bo  = (const float*)d_in[6];
    float* out = (float*)d_out;

    const size_t n_hid  = (size_t)CHID * HW;
    const size_t n_vout = (size_t)CQK * HW;
    const size_t n_x    = (size_t)CIN * HW;

    if (ws_size >= 4 * (n_hid + n_vout) * sizeof(float)) {
        float* hidden = (float*)d_ws;
        float* vout   = hidden + 4 * n_hid;
        k1_expand <<<dim3(HW / 256, CHID / 48, 4), 256, 0, stream>>>(
            x, wh, bh, hidden, n_x, n_hid);
        k2_fused  <<<dim3(H_IMG / 8, CQK, 4),      256, 0, stream>>>(
            hidden, wdw, bdw, vout, n_hid, n_vout);
        k3_project<<<dim3(HW / 256, 64 / 16, 4),   256, 0, stream>>>(
            vout, wo, bo, out, n_vout, n_x);
    } else {
        float* hidden = (float*)d_ws;
        float* vout   = hidden + n_hid;
        for (int b = 0; b < 4; ++b) {
            const float* xb = x + (size_t)b * n_x;
            float* ob       = out + (size_t)b * n_x;
            k1_expand <<<dim3(HW / 256, CHID / 48, 1), 256, 0, stream>>>(
                xb, wh, bh, hidden, 0, 0);
            k2_fused  <<<dim3(H_IMG / 8, CQK, 1),      256, 0, stream>>>(
                hidden, wdw, bdw, vout, 0, 0);
            k3_project<<<dim3(HW / 256, 64 / 16, 1),   256, 0, stream>>>(
                vout, wo, bo, ob, 0, 0);
        }
    }
}